// Round 10
// baseline (157.736 us; speedup 1.0000x reference)
//
#include <hip/hip_runtime.h>

// Problem constants (fixed by setup_inputs: bs=8, N=M=4096, C=128)
#define BS 8
#define NN 4096
#define MM 4096
#define CC 128
#define XT 128            // x rows per block
#define YT 128            // y rows per t-tile
#define MH 1024           // y rows per block (R25: 3 blocks/CU needs small LDS)
#define NMT (MH / YT)     // 8 y-tiles per block
#define NPH (2 * NMT)     // 16 half-K pipeline phases
#define NXT (NN / XT)     // 32 x-tiles
#define SLICE (YT * 64)   // ushorts per half-K slice (16 KB)

#define FINF_BITS 0x7F800000u

typedef __attribute__((ext_vector_type(8))) short bf16x8;
typedef __attribute__((ext_vector_type(4))) float f32x4;

#define WAITV0() asm volatile("s_waitcnt vmcnt(0)" ::: "memory")
// rule #18: pin scheduling around barriers
#define SCHED_FENCE() __builtin_amdgcn_sched_barrier(0)

// RNE fp32 -> bf16 (inputs are finite normals)
__device__ inline ushort f2bf(float f) {
    unsigned u = __float_as_uint(f);
    unsigned r = (u + 0x7FFFu + ((u >> 16) & 1u)) >> 16;
    return (ushort)r;
}

// ---------------------------------------------------------------------------
// prep (y only): fp32->bf16 copy of set2 + exact fp32 y norms +
// rowmin/colmin=+inf + out=0. 8 elem/thread.
// ---------------------------------------------------------------------------
__global__ void ch_prep(const float* __restrict__ y,
                        ushort* __restrict__ y16, float* __restrict__ yn,
                        unsigned* __restrict__ rowmin, unsigned* __restrict__ colmin,
                        float* __restrict__ out) {
    int gid = blockIdx.x * blockDim.x + threadIdx.x;   // 524288 threads
    size_t i = (size_t)gid * 8;

    float4 w0 = *(const float4*)(y + i);
    float4 w1 = *(const float4*)(y + i + 4);
    ushort h[8] = {f2bf(w0.x), f2bf(w0.y), f2bf(w0.z), f2bf(w0.w),
                   f2bf(w1.x), f2bf(w1.y), f2bf(w1.z), f2bf(w1.w)};
    *(bf16x8*)(y16 + i) = *(bf16x8*)h;
    float sy = w0.x * w0.x + w0.y * w0.y + w0.z * w0.z + w0.w * w0.w +
               w1.x * w1.x + w1.y * w1.y + w1.z * w1.z + w1.w * w1.w;

#pragma unroll
    for (int mask = 1; mask <= 8; mask <<= 1)
        sy += __shfl_xor(sy, mask, 64);
    if ((threadIdx.x & 15) == 0)
        yn[gid >> 4] = sy;                 // 16 threads per 128-ch row

    if (gid < BS * NN) rowmin[gid] = FINF_BITS;
    if (gid < BS * MM) colmin[gid] = FINF_BITS;
    if (gid == 0) out[0] = 0.0f;
}

// ---------------------------------------------------------------------------
// main kernel (R25 = R19 base, squeezed to 3 blocks/CU). Seven structures
// (R15..R24) all land 50-56us with MfmaUtil ~24 / VALUBusy ~37 at 2 waves/
// SIMD. VALUBusy decomposition: 37% x 7562 cyc/tile = 2800 cyc, of which
// only ~1120 is epilogue math -- the rest is accvgpr moves + staging addr
// recompute + glue; with 2 waves/SIMD the pipes serialize. The untested
// lever is 3 waves/SIMD ON the x-in-reg structure (R16 tested occupancy
// without it). Blockers were exact: regs 116+64=180 > 170, LDS 65KB > 53.
// Fixes: (a) LDS 41KB: 2-slice pool (32KB, = xs alias exactly) + MH 1024,
// grid z=4 -> 1024 blocks, 3/CU; (b) regs <=168: xnp evicted to LDS
// (R21's verified g-space epilogue: rm tracks fmaf(-2,a,yn), xnorm added
// at the flush), staging addresses hoisted (swizzle offset is loop-
// invariant: (tid>>3)*CC + ((tid&7)^((tid>>3)&7))*8; per call = base +
// s*4096), __launch_bounds__(256,3) pins the allocator. 2-slice staging:
// stage ph+1 while computing ph, vmcnt(0)+barrier per phase (loads are a
// full phase old -> drain ~free; 3 desynced blocks hide the rest).
// ---------------------------------------------------------------------------
__global__ __launch_bounds__(256, 3) void ch_tile(
    const float* __restrict__ Xf, const ushort* __restrict__ Y,
    const float* __restrict__ yn,
    unsigned* __restrict__ rowmin, unsigned* __restrict__ colmin) {

    __shared__ ushort pool[2 * SLICE];   // 32 KB: xs aliases both slices
    __shared__ unsigned coltile[MH];     // 4 KB
    __shared__ unsigned rowtile[XT];     // 0.5 KB
    __shared__ float xnorm[XT];          // 0.5 KB
    __shared__ float ynld[MH];           // 4 KB (block's y norms)

    const int b  = blockIdx.x;           // 0..7 -> XCD pin (linear id % 8 == b)
    const int xt = blockIdx.y;           // 0..31
    const int mh = blockIdx.z;           // 0..3
    const int n0 = xt * XT;
    const int m0 = mh * MH;
    const int tid  = threadIdx.x;        // 0..255
    const int lane = tid & 63;
    const int wave = tid >> 6;           // 0..3
    const int lc   = lane & 15;          // A/B row, C col
    const int quad = lane >> 4;          // k-chunk, C row group
    const int wm = wave >> 1;            // x half (0/1)
    const int wn = wave & 1;             // y half (0/1)

    const ushort* Yb = Y + ((size_t)b * MM + m0) * CC;

    // ---- prologue A: stage x tile fp32 -> bf16 -> swizzled LDS (xs = pool);
    //      x norms; y norms -> LDS; coltile/rowtile init ----
    ushort* xs = pool;
    const float* Xb = Xf + ((size_t)b * NN + n0) * CC;
    {
        float psum[8];
#pragma unroll
        for (int s = 0; s < 8; ++s) {
            int flat = s * 256 + tid;    // 2048 chunks = 128 rows x 16
            int r = flat >> 4, c = flat & 15;
            float4 v0 = *(const float4*)(Xb + (size_t)r * CC + c * 8);
            float4 v1 = *(const float4*)(Xb + (size_t)r * CC + c * 8 + 4);
            ushort h[8] = {f2bf(v0.x), f2bf(v0.y), f2bf(v0.z), f2bf(v0.w),
                           f2bf(v1.x), f2bf(v1.y), f2bf(v1.z), f2bf(v1.w)};
            *(bf16x8*)(xs + r * CC + (c ^ (r & 7)) * 8) = *(bf16x8*)h;
            psum[s] = v0.x * v0.x + v0.y * v0.y + v0.z * v0.z + v0.w * v0.w +
                      v1.x * v1.x + v1.y * v1.y + v1.z * v1.z + v1.w * v1.w;
        }
#pragma unroll
        for (int mask = 1; mask <= 8; mask <<= 1)
#pragma unroll
            for (int s = 0; s < 8; ++s)
                psum[s] += __shfl_xor(psum[s], mask, 64);
        if ((tid & 15) == 0) {
#pragma unroll
            for (int s = 0; s < 8; ++s)
                xnorm[s * 16 + (tid >> 4)] = psum[s];
        }
    }
    {
        const float* ynb = yn + (size_t)b * MM + m0;
#pragma unroll
        for (int s = 0; s < MH / 256; ++s)
            ynld[s * 256 + tid] = ynb[s * 256 + tid];
    }
    for (int c2 = tid; c2 < MH; c2 += 256) coltile[c2] = FINF_BITS;
    if (tid < XT) rowtile[tid] = FINF_BITS;

    __syncthreads();   // xs + xnorm + ynld + coltile ready

    // ---- prologue B: hoist this wave's A operand into registers ----
    bf16x8 af[4][4];   // [k-chunk32 kt][row-group i] : 64 VGPR
    const int xrow = (wm * 64 + lc) * CC;
    const int xsw  = lc & 7;
#pragma unroll
    for (int kt = 0; kt < 4; ++kt)
#pragma unroll
        for (int i = 0; i < 4; ++i)
            af[kt][i] = *(const bf16x8*)(xs + xrow + i * 16 * CC +
                                         ((kt * 4 + quad) ^ xsw) * 8);

    float rm[4][4];    // min over y of g = fmaf(-2,xy,yn); xnorm added at flush
#pragma unroll
    for (int i = 0; i < 4; ++i)
#pragma unroll
        for (int r = 0; r < 4; ++r) rm[i][r] = __builtin_inff();

    __syncthreads();   // all waves done reading xs: pool may be overwritten

    // ---- hoisted staging addressing (loop-invariant swizzle offset) ----
    // chunk f = s*256+tid -> r = s*32 + (tid>>3), cslot = tid&7;
    // off = r*CC + (cslot ^ (r&7))*8 ; (r&7)==(tid>>3)&7 since s*32 % 8 == 0
    const int tr = tid >> 3;
    const size_t poff = (size_t)tr * CC + (((tid & 7) ^ (tr & 7)) * 8);
    const ushort* gbase = Yb + poff;               // + tile*YT*CC + half*64 + s*4096
    ushort* lbase = pool + (size_t)(wave * 64) * 8; // + slice sel + s*2048 elems

    // ---- prologue C: stage slice 0 (tile0, half0) into buffer 0 ----
#pragma unroll
    for (int s = 0; s < 4; ++s)
        __builtin_amdgcn_global_load_lds(
            (const __attribute__((address_space(1))) void*)(gbase + s * 4096),
            (__attribute__((address_space(3))) void*)(lbase + s * 2048), 16, 0, 0);
    WAITV0();
    __builtin_amdgcn_s_barrier();
    SCHED_FENCE();

    const f32x4 z = {0.f, 0.f, 0.f, 0.f};

#pragma unroll 1
    for (int t = 0; t < NMT; ++t) {
        f32x4 acc[4][4];
        float ynr[4];

#pragma unroll
        for (int h = 0; h < 2; ++h) {
            const int ph = 2 * t + h;
            const ushort* ybuf = pool + (ph & 1) * SLICE;

            // stage slice ph+1 into the other buffer (safe: all waves left it
            // at the barrier ending ph-1)
            if (ph + 1 < NPH) {
                const ushort* gs = gbase + (size_t)((ph + 1) >> 1) * (YT * CC) +
                                   ((ph + 1) & 1) * 64;
                ushort* ls = lbase + ((ph + 1) & 1) * SLICE;
#pragma unroll
                for (int s = 0; s < 4; ++s)
                    __builtin_amdgcn_global_load_lds(
                        (const __attribute__((address_space(1))) void*)(gs + s * 4096),
                        (__attribute__((address_space(3))) void*)(ls + s * 2048),
                        16, 0, 0);
            }

            if (h == 0) {
#pragma unroll
                for (int j = 0; j < 4; ++j)       // LDS read: no vmcnt impact
                    ynr[j] = ynld[t * YT + wn * 64 + j * 16 + lc];
            }

#pragma unroll
            for (int s2 = 0; s2 < 2; ++s2) {
                const int ktg = h * 2 + s2;
                bf16x8 yf[4];
                const int cy = ((s2 * 4 + quad) ^ xsw) * 8;
#pragma unroll
                for (int j = 0; j < 4; ++j)
                    yf[j] = *(const bf16x8*)(ybuf + (wn * 64 + j * 16 + lc) * 64 + cy);
#pragma unroll
                for (int j = 0; j < 4; ++j)
#pragma unroll
                    for (int i = 0; i < 4; ++i)
                        acc[i][j] = __builtin_amdgcn_mfma_f32_16x16x32_bf16(
                            af[ktg][i], yf[j], (ktg == 0) ? z : acc[i][j], 0, 0, 0);
            }

            if (h == 1) {
                // ---- epilogue in g-space: g = yn - 2xy; d^2 = xnorm + g ----
                float cmv[4];
#pragma unroll
                for (int j = 0; j < 4; ++j) cmv[j] = __builtin_inff();
#pragma unroll
                for (int i = 0; i < 4; ++i) {
                    float4 xq = *(const float4*)(&xnorm[wm * 64 + i * 16 + quad * 4]);
#pragma unroll
                    for (int j = 0; j < 4; ++j) {
                        f32x4 a = acc[i][j];
                        float g0 = fmaf(-2.0f, a[0], ynr[j]);
                        float g1 = fmaf(-2.0f, a[1], ynr[j]);
                        float g2 = fmaf(-2.0f, a[2], ynr[j]);
                        float g3 = fmaf(-2.0f, a[3], ynr[j]);
                        rm[i][0] = fminf(rm[i][0], g0);
                        rm[i][1] = fminf(rm[i][1], g1);
                        rm[i][2] = fminf(rm[i][2], g2);
                        rm[i][3] = fminf(rm[i][3], g3);
                        float m01 = fminf(xq.x + g0, xq.y + g1);
                        float m23 = fminf(xq.z + g2, xq.w + g3);
                        cmv[j] = fminf(cmv[j], fminf(m01, m23));
                    }
                }
#pragma unroll
                for (int mask = 16; mask <= 32; mask <<= 1)
#pragma unroll
                    for (int j = 0; j < 4; ++j)
                        cmv[j] = fminf(cmv[j], __shfl_xor(cmv[j], mask, 64));
                if (quad == 0) {
#pragma unroll
                    for (int j = 0; j < 4; ++j)
                        atomicMin(&coltile[t * YT + wn * 64 + j * 16 + lc],
                                  __float_as_uint(fmaxf(cmv[j], 0.0f)));
                }
            }

            SCHED_FENCE();
            WAITV0();
            __builtin_amdgcn_s_barrier();
            SCHED_FENCE();
        }
    }

    // ---- row mins: reduce g across the 16 lc lanes, add xnorm, flush ----
#pragma unroll
    for (int mask = 1; mask <= 8; mask <<= 1)
#pragma unroll
        for (int i = 0; i < 4; ++i)
#pragma unroll
            for (int r = 0; r < 4; ++r)
                rm[i][r] = fminf(rm[i][r], __shfl_xor(rm[i][r], mask, 64));
    if (lc == 0) {
#pragma unroll
        for (int i = 0; i < 4; ++i) {
            float4 xq = *(const float4*)(&xnorm[wm * 64 + i * 16 + quad * 4]);
            float xr[4] = {xq.x, xq.y, xq.z, xq.w};
#pragma unroll
            for (int r = 0; r < 4; ++r)
                atomicMin(&rowtile[wm * 64 + i * 16 + quad * 4 + r],
                          __float_as_uint(fmaxf(rm[i][r] + xr[r], 0.0f)));
        }
    }

    // ---- flush tile minima with global atomics ----
    __syncthreads();
    if (tid < XT)
        atomicMin(&rowmin[(size_t)b * NN + n0 + tid], rowtile[tid]);
    for (int c2 = tid; c2 < MH; c2 += 256)
        atomicMin(&colmin[(size_t)b * MM + m0 + c2], coltile[c2]);
}

// ---------------------------------------------------------------------------
// finalize: total = (sum w1*sqrt(rowmin) + sum w2*sqrt(colmin)) / 2
// ---------------------------------------------------------------------------
__global__ void ch_finalize(const unsigned* __restrict__ rowmin,
                            const unsigned* __restrict__ colmin,
                            const float* __restrict__ w1,
                            const float* __restrict__ w2,
                            float* __restrict__ out) {
    int i = blockIdx.x * blockDim.x + threadIdx.x;
    int stride = gridDim.x * blockDim.x;
    float s = 0.f;
    for (int idx = i; idx < BS * NN; idx += stride)
        s += w1[idx] * sqrtf(__uint_as_float(rowmin[idx])) +
             w2[idx] * sqrtf(__uint_as_float(colmin[idx]));
#pragma unroll
    for (int off = 32; off > 0; off >>= 1) s += __shfl_down(s, off, 64);
    __shared__ float ls[4];
    int lane = threadIdx.x & 63, wv = threadIdx.x >> 6;
    if (lane == 0) ls[wv] = s;
    __syncthreads();
    if (threadIdx.x == 0) {
        float t = ls[0] + ls[1] + ls[2] + ls[3];
        atomicAdd(out, 0.5f * t);
    }
}

extern "C" void kernel_launch(void* const* d_in, const int* in_sizes, int n_in,
                              void* d_out, int out_size, void* d_ws, size_t ws_size,
                              hipStream_t stream) {
    const float* set1 = (const float*)d_in[0];
    const float* set2 = (const float*)d_in[1];
    const float* w1   = (const float*)d_in[2];
    const float* w2   = (const float*)d_in[3];
    float* out = (float*)d_out;

    // workspace layout (~8.5 MiB)
    ushort*   y16    = (ushort*)d_ws;                        // BS*MM*CC bf16 (8 MB)
    float*    yn     = (float*)(y16 + (size_t)BS * MM * CC); // 128 KB
    unsigned* rowmin = (unsigned*)(yn + BS * MM);            // 128 KB (d^2 bits)
    unsigned* colmin = rowmin + BS * NN;                     // 128 KB (d^2 bits)

    ch_prep<<<BS * MM * CC / 8 / 256, 256, 0, stream>>>(
        set2, y16, yn, rowmin, colmin, out);

    dim3 grid(BS, NXT, MM / MH);   // b fastest -> linear id % 8 == b == XCD
    ch_tile<<<grid, 256, 0, stream>>>(set1, y16, yn, rowmin, colmin);

    ch_finalize<<<64, 256, 0, stream>>>(rowmin, colmin, w1, w2, out);
}